// Round 1
// baseline (315.432 us; speedup 1.0000x reference)
//
#include <hip/hip_runtime.h>

#define B 4
#define C 19
#define H 192
#define W 192
// 40 / ln(2): exp(-40*x) == exp2(-THETA_LOG2E*x)
#define THETA_LOG2E 57.70780163555855f

// -------- setup: hc = cumsum(relu(edge), axis=H), wc = cumsum(relu(edge), axis=W) --------
__global__ void k_cumsum(const float* __restrict__ edge,
                         float* __restrict__ hc, float* __restrict__ wc) {
    int tid = blockIdx.x * blockDim.x + threadIdx.x;
    const int njobs = B * W;
    if (tid < njobs) {
        // column cumsum -> hc[b, :, j]
        int b = tid / W, j = tid % W;
        const float* ep = edge + b * H * W + j;
        float* hp = hc + b * H * W + j;
        float s = 0.f;
        #pragma unroll 8
        for (int t = 0; t < H; ++t) {
            float v = ep[t * W];
            v = v > 0.f ? v : 0.f;
            s += v;
            hp[t * W] = s;
        }
    } else if (tid < 2 * njobs) {
        // row cumsum -> wc[b, i, :]
        int r = tid - njobs;
        int b = r / H, i = r % H;
        const float* ep = edge + (b * H + i) * W;
        float* wp = wc + (b * H + i) * W;
        float s = 0.f;
        #pragma unroll 8
        for (int ss = 0; ss < W; ++ss) {
            float v = ep[ss];
            v = v > 0.f ? v : 0.f;
            s += v;
            wp[ss] = s;
        }
    }
}

// -------- setup: softmax denominator D[b,i,j] (iteration-invariant) --------
__global__ __launch_bounds__(W) void k_denom(const float* __restrict__ hc,
                                             const float* __restrict__ wc,
                                             float* __restrict__ Dm) {
    int b = blockIdx.x / H;
    int i = blockIdx.x % H;
    int j = threadIdx.x;  // 192
    __shared__ float wcr[W];
    wcr[j] = wc[(b * H + i) * W + j];
    __syncthreads();
    float hij = hc[(b * H + i) * W + j];
    float wcj = wcr[j];
    float acc = 0.f;
    const float* hcol = hc + b * H * W + j;
    #pragma unroll 4
    for (int t = 0; t < H; ++t) {
        float d = fabsf(hcol[t * W] - hij);   // coalesced across j
        acc += exp2f(-THETA_LOG2E * d);
    }
    #pragma unroll 4
    for (int s = 0; s < W; ++s) {
        float d = fabsf(wcr[s] - wcj);
        acc += exp2f(-THETA_LOG2E * d);
    }
    // subtract the excluded diagonal term (s == j contributes exp(0) == 1)
    Dm[(b * H + i) * W + j] = acc - 1.0f;
}

// -------- per iteration, phase 1: out_c[b,c,i,j] = sum_t exp(-theta*|hc[t,j]-hc[i,j]|) * feat[b,c,t,j] --------
__global__ __launch_bounds__(W) void k_col(const float* __restrict__ feat,
                                           const float* __restrict__ hc,
                                           float* __restrict__ outc) {
    int b = blockIdx.x / W;
    int j = blockIdx.x % W;
    int tid = threadIdx.x;  // 192, = output row i
    __shared__ float hcc[H];
    __shared__ float FcT[H][20];  // [t][c], padded to 20 for aligned float4
    hcc[tid] = hc[(b * H + tid) * W + j];
    for (int idx = tid; idx < C * H; idx += W) {
        int c = idx / H, t = idx % H;
        FcT[t][c] = feat[((b * C + c) * H + t) * W + j];  // strided gather (stride W)
    }
    __syncthreads();
    float hci = hcc[tid];
    float acc[C];
    #pragma unroll
    for (int c = 0; c < C; ++c) acc[c] = 0.f;
    #pragma unroll 2
    for (int t = 0; t < H; ++t) {
        float p = exp2f(-THETA_LOG2E * fabsf(hcc[t] - hci));
        float fv[20];
        #pragma unroll
        for (int q = 0; q < 5; ++q)
            ((float4*)fv)[q] = ((const float4*)&FcT[t][0])[q];
        #pragma unroll
        for (int c = 0; c < C; ++c) acc[c] += p * fv[c];
    }
    int i = tid;
    #pragma unroll
    for (int c = 0; c < C; ++c)
        outc[((b * C + c) * H + i) * W + j] = acc[c];
}

// -------- per iteration, phase 2: out = (outc + row-attention) / D  (featout may alias featin) --------
__global__ __launch_bounds__(W) void k_row(const float* __restrict__ featin,
                                           const float* __restrict__ wc,
                                           const float* __restrict__ Dm,
                                           const float* __restrict__ outc,
                                           float* __restrict__ featout) {
    int b = blockIdx.x / H;
    int i = blockIdx.x % H;
    int j = threadIdx.x;  // 192
    __shared__ float wcr[W];
    __shared__ float FrT[W][20];  // [s][c]
    wcr[j] = wc[(b * H + i) * W + j];
    for (int idx = j; idx < C * W; idx += W) {
        int c = idx / W, s = idx % W;
        FrT[s][c] = featin[((b * C + c) * H + i) * W + s];  // coalesced row loads
    }
    __syncthreads();
    float wcj = wcr[j];
    float acc[C];
    #pragma unroll
    for (int c = 0; c < C; ++c) acc[c] = 0.f;
    #pragma unroll 2
    for (int s = 0; s < W; ++s) {
        float q = exp2f(-THETA_LOG2E * fabsf(wcr[s] - wcj));
        float fv[20];
        #pragma unroll
        for (int qq = 0; qq < 5; ++qq)
            ((float4*)fv)[qq] = ((const float4*)&FrT[s][0])[qq];
        #pragma unroll
        for (int c = 0; c < C; ++c) acc[c] += q * fv[c];
    }
    float rD = 1.0f / Dm[(b * H + i) * W + j];
    #pragma unroll
    for (int c = 0; c < C; ++c) {
        // remove diagonal s==j (its weight was exactly 1), add column part, normalize
        float v = acc[c] - FrT[j][c];
        v += outc[((b * C + c) * H + i) * W + j];
        featout[((b * C + c) * H + i) * W + j] = v * rD;
    }
}

extern "C" void kernel_launch(void* const* d_in, const int* in_sizes, int n_in,
                              void* d_out, int out_size, void* d_ws, size_t ws_size,
                              hipStream_t stream) {
    const float* mask = (const float*)d_in[0];
    const float* edge = (const float*)d_in[1];
    float* out = (float*)d_out;

    float* hc  = (float*)d_ws;
    float* wcb = hc + B * H * W;
    float* Dm  = wcb + B * H * W;
    float* wsC = Dm + B * H * W;   // [B][C][H][W] scratch for out_c

    const int ITER = 3;  // setup_inputs fixes iter = 3

    k_cumsum<<<6, 256, 0, stream>>>(edge, hc, wcb);
    k_denom<<<B * H, W, 0, stream>>>(hc, wcb, Dm);

    // iter 1: mask -> out
    k_col<<<B * W, W, 0, stream>>>(mask, hc, wsC);
    k_row<<<B * H, W, 0, stream>>>(mask, wcb, Dm, wsC, out);
    // iters 2..ITER: out -> out (in-place safe per-row)
    for (int it = 1; it < ITER; ++it) {
        k_col<<<B * W, W, 0, stream>>>(out, hc, wsC);
        k_row<<<B * H, W, 0, stream>>>(out, wcb, Dm, wsC, out);
    }
}

// Round 2
// 225.614 us; speedup vs baseline: 1.3981x; 1.3981x over previous
//
#include <hip/hip_runtime.h>

#define B 4
#define C 19
#define H 192
#define W 192
// 40 / ln(2): exp(-40*x) == exp2(-THETA_LOG2E*x)
#define THETA_LOG2E 57.70780163555855f

// -------- setup: hc/wc cumsums (for denom) + dmat = exp2(-theta*relu(edge)) --------
__global__ void k_prep(const float* __restrict__ edge,
                       float* __restrict__ hc, float* __restrict__ wc,
                       float* __restrict__ dmat) {
    int tid = blockIdx.x * blockDim.x + threadIdx.x;
    const int njobs = B * W;
    if (tid < njobs) {
        // column cumsum -> hc[b, :, j]
        int b = tid / W, j = tid % W;
        const float* ep = edge + b * H * W + j;
        float* hp = hc + b * H * W + j;
        float s = 0.f;
        #pragma unroll 8
        for (int t = 0; t < H; ++t) {
            float v = ep[t * W];
            v = v > 0.f ? v : 0.f;
            s += v;
            hp[t * W] = s;
        }
    } else if (tid < 2 * njobs) {
        // row cumsum -> wc[b, i, :], and dmat[b, i, :]
        int r = tid - njobs;
        int b = r / H, i = r % H;
        const float* ep = edge + (b * H + i) * W;
        float* wp = wc + (b * H + i) * W;
        float* dp = dmat + (b * H + i) * W;
        float s = 0.f;
        #pragma unroll 8
        for (int ss = 0; ss < W; ++ss) {
            float v = ep[ss];
            v = v > 0.f ? v : 0.f;
            s += v;
            wp[ss] = s;
            dp[ss] = exp2f(-THETA_LOG2E * v);
        }
    }
}

// -------- setup: softmax denominator D[b,i,j] (iteration-invariant) --------
__global__ __launch_bounds__(W) void k_denom(const float* __restrict__ hc,
                                             const float* __restrict__ wc,
                                             float* __restrict__ Dm) {
    int b = blockIdx.x / H;
    int i = blockIdx.x % H;
    int j = threadIdx.x;  // 192
    __shared__ float wcr[W];
    wcr[j] = wc[(b * H + i) * W + j];
    __syncthreads();
    float hij = hc[(b * H + i) * W + j];
    float wcj = wcr[j];
    float acc = 0.f;
    const float* hcol = hc + b * H * W + j;
    #pragma unroll 4
    for (int t = 0; t < H; ++t) {
        float d = fabsf(hcol[t * W] - hij);   // coalesced across j
        acc += exp2f(-THETA_LOG2E * d);
    }
    #pragma unroll 4
    for (int s = 0; s < W; ++s) {
        float d = fabsf(wcr[s] - wcj);
        acc += exp2f(-THETA_LOG2E * d);
    }
    // subtract the excluded diagonal term (s == j contributes exp(0) == 1)
    Dm[(b * H + i) * W + j] = acc - 1.0f;
}

// -------- per iter, phase 1: backward column scan Sf[i] = f[i] + d[i+1]*Sf[i+1] --------
// thread per (b,c,j); all loads/stores coalesced across j
__global__ __launch_bounds__(64) void k_colbwd(const float* __restrict__ f,
                                               const float* __restrict__ dmat,
                                               float* __restrict__ sfc) {
    int tid = blockIdx.x * 64 + threadIdx.x;  // B*C*W = 14592
    int j = tid % W;
    int c = (tid / W) % C;
    int b = tid / (W * C);
    const float* fp = f + ((size_t)(b * C + c) * H) * W + j;
    const float* dp = dmat + (size_t)b * H * W + j;
    float* op = sfc + ((size_t)(b * C + c) * H) * W + j;
    float sf = fp[191 * W];
    op[191 * W] = sf;
    #pragma unroll 4
    for (int i = 190; i >= 0; --i) {
        sf = sf * dp[(i + 1) * W] + fp[i * W];
        op[i * W] = sf;
    }
}

// -------- per iter, phase 2: forward column scan + combine to colsum (in place over sfc) --------
// colsum[i] = Z[i] - f[i] + Sf[i]  (full column attention, incl diagonal)
__global__ __launch_bounds__(64) void k_colfwd(const float* __restrict__ f,
                                               const float* __restrict__ dmat,
                                               float* __restrict__ sfc) {
    int tid = blockIdx.x * 64 + threadIdx.x;
    int j = tid % W;
    int c = (tid / W) % C;
    int b = tid / (W * C);
    const float* fp = f + ((size_t)(b * C + c) * H) * W + j;
    const float* dp = dmat + (size_t)b * H * W + j;
    float* op = sfc + ((size_t)(b * C + c) * H) * W + j;
    float z = 0.f;
    #pragma unroll 4
    for (int i = 0; i < H; ++i) {
        float fv = fp[i * W];
        z = z * dp[i * W] + fv;
        op[i * W] = z - fv + op[i * W];
    }
}

// -------- per iter, phase 3: in-register row scan (Kogge-Stone over affine pairs) + combine --------
// wave per (b,c,i); lane owns s = {3l, 3l+1, 3l+2}
// out = (colsum + Z_row + Sf_row - 2*f) / D
__global__ __launch_bounds__(256) void k_rowcomb(const float* __restrict__ f,
                                                 const float* __restrict__ dmat,
                                                 const float* __restrict__ Dm,
                                                 const float* __restrict__ colsum,
                                                 float* __restrict__ out) {
    int wid = (blockIdx.x * 256 + threadIdx.x) >> 6;   // B*C*H = 14592 waves
    int lane = threadIdx.x & 63;
    int i = wid % H;
    int c = (wid / H) % C;
    int b = wid / (H * C);
    const size_t rb = ((size_t)(b * C + c) * H + i) * W;
    const int db = (b * H + i) * W;
    const int s0 = 3 * lane;

    float f0 = f[rb + s0], f1 = f[rb + s0 + 1], f2 = f[rb + s0 + 2];
    float d0 = dmat[db + s0], d1 = dmat[db + s0 + 1], d2 = dmat[db + s0 + 2];
    float d3 = (lane < 63) ? dmat[db + s0 + 3] : 0.f;

    // ---- forward scan: Z[s] = d[s]*Z[s-1] + f[s], Z[-1] = 0
    // per-lane segment transform (P, Q): Z_out = P*Z_in + Q
    float P = d0 * d1 * d2;
    float Q = (f0 * d1 + f1) * d2 + f2;
    #pragma unroll
    for (int off = 1; off < 64; off <<= 1) {
        float Pp = __shfl_up(P, off);
        float Qp = __shfl_up(Q, off);
        if (lane >= off) { Q = Qp * P + Q; P = Pp * P; }
    }
    float zin = __shfl_up(Q, 1);
    if (lane == 0) zin = 0.f;
    float zA = zin * d0 + f0;
    float zB = zA * d1 + f1;
    float zC = zB * d2 + f2;

    // ---- backward scan: Sf[s] = d[s+1]*Sf[s+1] + f[s], Sf[192] = 0
    float Pb = d3 * d2 * d1;
    float Qb = (f2 * d2 + f1) * d1 + f0;
    #pragma unroll
    for (int off = 1; off < 64; off <<= 1) {
        float Pp = __shfl_down(Pb, off);
        float Qp = __shfl_down(Qb, off);
        if (lane < 64 - off) { Qb = Qp * Pb + Qb; Pb = Pp * Pb; }
    }
    float sin_ = __shfl_down(Qb, 1);
    if (lane == 63) sin_ = 0.f;
    float sC = sin_ * d3 + f2;
    float sB = sC * d2 + f1;
    float sA = sB * d1 + f0;

    // ---- combine: out = (colsum + (Z + Sf - f) - f) / D
    float rd0 = 1.0f / Dm[db + s0];
    float rd1 = 1.0f / Dm[db + s0 + 1];
    float rd2 = 1.0f / Dm[db + s0 + 2];
    out[rb + s0]     = (colsum[rb + s0]     + zA + sA - 2.f * f0) * rd0;
    out[rb + s0 + 1] = (colsum[rb + s0 + 1] + zB + sB - 2.f * f1) * rd1;
    out[rb + s0 + 2] = (colsum[rb + s0 + 2] + zC + sC - 2.f * f2) * rd2;
}

extern "C" void kernel_launch(void* const* d_in, const int* in_sizes, int n_in,
                              void* d_out, int out_size, void* d_ws, size_t ws_size,
                              hipStream_t stream) {
    const float* mask = (const float*)d_in[0];
    const float* edge = (const float*)d_in[1];
    float* out = (float*)d_out;

    float* hc   = (float*)d_ws;                 // [B,H,W]
    float* wcb  = hc + B * H * W;               // [B,H,W]
    float* Dm   = wcb + B * H * W;              // [B,H,W]
    float* dmat = Dm + B * H * W;               // [B,H,W]
    float* csum = dmat + B * H * W;             // [B,C,H,W] scratch (Sf, then colsum)

    const int ITER = 3;

    k_prep<<<6, 256, 0, stream>>>(edge, hc, wcb, dmat);
    k_denom<<<B * H, W, 0, stream>>>(hc, wcb, Dm);

    const int colgrid = (B * C * W) / 64;       // 228
    const int rowgrid = (B * C * H) / 4;        // 3648 blocks of 4 waves

    // iter 1: mask -> out
    k_colbwd<<<colgrid, 64, 0, stream>>>(mask, dmat, csum);
    k_colfwd<<<colgrid, 64, 0, stream>>>(mask, dmat, csum);
    k_rowcomb<<<rowgrid, 256, 0, stream>>>(mask, dmat, Dm, csum, out);
    // iters 2..3: out -> out (per-row/col ownership makes in-place safe)
    for (int it = 1; it < ITER; ++it) {
        k_colbwd<<<colgrid, 64, 0, stream>>>(out, dmat, csum);
        k_colfwd<<<colgrid, 64, 0, stream>>>(out, dmat, csum);
        k_rowcomb<<<rowgrid, 256, 0, stream>>>(out, dmat, Dm, csum, out);
    }
}

// Round 3
// 65.095 us; speedup vs baseline: 4.8457x; 3.4659x over previous
//
#include <hip/hip_runtime.h>

#define B 4
#define C 19
#define H 192
#define W 192
// 40 / ln(2): exp(-40*x) == exp2(-THETA_LOG2E*x)
#define THETA_LOG2E 57.70780163555855f

#define SEG 8
#define ROWS 24   // H / SEG
#define JT 64     // columns per block

// -------- setup: dmat = exp2(-theta*relu(edge)), elementwise --------
__global__ __launch_bounds__(256) void k_prep(const float* __restrict__ edge,
                                              float* __restrict__ dmat) {
    int idx = blockIdx.x * 256 + threadIdx.x;       // B*H*W/4 = 36864 float4s
    float4 e = ((const float4*)edge)[idx];
    float4 o;
    o.x = exp2f(-THETA_LOG2E * fmaxf(e.x, 0.f));
    o.y = exp2f(-THETA_LOG2E * fmaxf(e.y, 0.f));
    o.z = exp2f(-THETA_LOG2E * fmaxf(e.z, 0.f));
    o.w = exp2f(-THETA_LOG2E * fmaxf(e.w, 0.f));
    ((float4*)dmat)[idx] = o;
}

// -------- segmented column scan (fwd + bwd fused) --------
// Z[i] = d[i]*Z[i-1] + f[i];  Sf[i] = d[i+1]*Sf[i+1] + f[i];  out = Z + Sf - f
// UNIT_F: f == 1 everywhere (denominator column part), out = Z + S - 1
template <bool UNIT_F>
__global__ __launch_bounds__(512) void k_colscan(const float* __restrict__ f,
                                                 const float* __restrict__ dmat,
                                                 float* __restrict__ outp) {
    int blk = blockIdx.x;
    int jt = blk % (W / JT);
    int rest = blk / (W / JT);
    int c = UNIT_F ? 0 : (rest % C);
    int b = UNIT_F ? rest : (rest / C);
    int jl = threadIdx.x & 63;
    int seg = threadIdx.x >> 6;
    int j = jl + jt * JT;
    int i0 = seg * ROWS;

    const float* dp = dmat + ((size_t)b * H + i0) * W + j;
    const float* fp = UNIT_F ? nullptr : (f + (((size_t)(b * C + c) * H) + i0) * W + j);
    float* op = UNIT_F ? (outp + ((size_t)b * H + i0) * W + j)
                       : (outp + (((size_t)(b * C + c) * H) + i0) * W + j);

    float dr[ROWS + 1];
    float fr[ROWS];
    #pragma unroll
    for (int r = 0; r < ROWS; ++r) dr[r] = dp[r * W];
    dr[ROWS] = (i0 + ROWS < H) ? dp[ROWS * W] : 0.f;
    if (!UNIT_F) {
        #pragma unroll
        for (int r = 0; r < ROWS; ++r) fr[r] = fp[r * W];
    }

    // per-segment affine transforms: Z_out = Pf*Z_in + Qf (fwd), Sf_out = Pb*Sf_in + Qb (bwd)
    float Pf = 1.f, Qf = 0.f;
    #pragma unroll
    for (int r = 0; r < ROWS; ++r) {
        float fv = UNIT_F ? 1.f : fr[r];
        Qf = Qf * dr[r] + fv;
        Pf *= dr[r];
    }
    float Pb = 1.f, Qb = 0.f;
    #pragma unroll
    for (int r = ROWS - 1; r >= 0; --r) {
        float fv = UNIT_F ? 1.f : fr[r];
        Qb = Qb * dr[r + 1] + fv;
        Pb *= dr[r + 1];
    }

    __shared__ float sPf[SEG][JT], sQf[SEG][JT], sPb[SEG][JT], sQb[SEG][JT];
    sPf[seg][jl] = Pf; sQf[seg][jl] = Qf;
    sPb[seg][jl] = Pb; sQb[seg][jl] = Qb;
    __syncthreads();
    // serial compose across the 8 segments (cheap; 64 threads each direction)
    if (seg == 0) {
        float P = sPf[0][jl], Q = sQf[0][jl];
        for (int s2 = 1; s2 < SEG; ++s2) {
            float Pc = sPf[s2][jl], Qc = sQf[s2][jl];
            Q = Q * Pc + Qc;           // prefix-then-current composition
            P = P * Pc;
            sPf[s2][jl] = P; sQf[s2][jl] = Q;   // inclusive prefix transform
        }
    } else if (seg == 1) {
        float P = sPb[SEG - 1][jl], Q = sQb[SEG - 1][jl];
        for (int s2 = SEG - 2; s2 >= 0; --s2) {
            float Pc = sPb[s2][jl], Qc = sQb[s2][jl];
            Q = Q * Pc + Qc;
            P = P * Pc;
            sPb[s2][jl] = P; sQb[s2][jl] = Q;   // inclusive suffix transform
        }
    }
    __syncthreads();
    float Zin = (seg == 0) ? 0.f : sQf[seg - 1][jl];
    float Sin = (seg == SEG - 1) ? 0.f : sQb[seg + 1][jl];

    // re-walk with true boundary values
    float zarr[ROWS];
    float z = Zin;
    #pragma unroll
    for (int r = 0; r < ROWS; ++r) {
        float fv = UNIT_F ? 1.f : fr[r];
        z = z * dr[r] + fv;
        zarr[r] = z;
    }
    float s = Sin;
    #pragma unroll
    for (int r = ROWS - 1; r >= 0; --r) {
        float fv = UNIT_F ? 1.f : fr[r];
        s = s * dr[r + 1] + fv;
        op[r * W] = zarr[r] + s - fv;   // diagonal counted once
    }
}

// -------- setup: Dm = Dcol + Drow - 1, Drow via in-register row scan with f=1 --------
__global__ __launch_bounds__(256) void k_drow(const float* __restrict__ dmat,
                                              const float* __restrict__ dcol,
                                              float* __restrict__ Dm) {
    int wid = (blockIdx.x * 256 + threadIdx.x) >> 6;  // B*H = 768 waves
    int lane = threadIdx.x & 63;
    int i = wid % H, b = wid / H;
    int base = (b * H + i) * W;
    int s0 = 3 * lane;
    float d0 = dmat[base + s0], d1 = dmat[base + s0 + 1], d2 = dmat[base + s0 + 2];
    float d3 = (lane < 63) ? dmat[base + s0 + 3] : 0.f;

    // forward, f=1: z = z*d + 1
    float P = d0 * d1 * d2;
    float Q = d1 * d2 + d2 + 1.f;
    #pragma unroll
    for (int off = 1; off < 64; off <<= 1) {
        float Pp = __shfl_up(P, off);
        float Qp = __shfl_up(Q, off);
        if (lane >= off) { Q = Qp * P + Q; P = Pp * P; }
    }
    float zin = __shfl_up(Q, 1);
    if (lane == 0) zin = 0.f;
    float zA = zin * d0 + 1.f;
    float zB = zA * d1 + 1.f;
    float zC = zB * d2 + 1.f;

    // backward, f=1: s = s*d[next] + 1
    float Pb = d3 * d2 * d1;
    float Qb = d2 * d1 + d1 + 1.f;
    #pragma unroll
    for (int off = 1; off < 64; off <<= 1) {
        float Pp = __shfl_down(Pb, off);
        float Qp = __shfl_down(Qb, off);
        if (lane < 64 - off) { Qb = Qp * Pb + Qb; Pb = Pp * Pb; }
    }
    float sin_ = __shfl_down(Qb, 1);
    if (lane == 63) sin_ = 0.f;
    float sC = sin_ * d3 + 1.f;
    float sB = sC * d2 + 1.f;
    float sA = sB * d1 + 1.f;

    // rowD = z + s - 1 ; Dm = dcol + rowD - 1
    Dm[base + s0]     = dcol[base + s0]     + zA + sA - 2.f;
    Dm[base + s0 + 1] = dcol[base + s0 + 1] + zB + sB - 2.f;
    Dm[base + s0 + 2] = dcol[base + s0 + 2] + zC + sC - 2.f;
}

// -------- per iter: in-register row scan + combine --------
__global__ __launch_bounds__(256) void k_rowcomb(const float* __restrict__ f,
                                                 const float* __restrict__ dmat,
                                                 const float* __restrict__ Dm,
                                                 const float* __restrict__ colsum,
                                                 float* __restrict__ out) {
    int wid = (blockIdx.x * 256 + threadIdx.x) >> 6;   // B*C*H = 14592 waves
    int lane = threadIdx.x & 63;
    int i = wid % H;
    int c = (wid / H) % C;
    int b = wid / (H * C);
    const size_t rb = ((size_t)(b * C + c) * H + i) * W;
    const int db = (b * H + i) * W;
    const int s0 = 3 * lane;

    float f0 = f[rb + s0], f1 = f[rb + s0 + 1], f2 = f[rb + s0 + 2];
    float d0 = dmat[db + s0], d1 = dmat[db + s0 + 1], d2 = dmat[db + s0 + 2];
    float d3 = (lane < 63) ? dmat[db + s0 + 3] : 0.f;

    // forward scan: Z[s] = d[s]*Z[s-1] + f[s]
    float P = d0 * d1 * d2;
    float Q = (f0 * d1 + f1) * d2 + f2;
    #pragma unroll
    for (int off = 1; off < 64; off <<= 1) {
        float Pp = __shfl_up(P, off);
        float Qp = __shfl_up(Q, off);
        if (lane >= off) { Q = Qp * P + Q; P = Pp * P; }
    }
    float zin = __shfl_up(Q, 1);
    if (lane == 0) zin = 0.f;
    float zA = zin * d0 + f0;
    float zB = zA * d1 + f1;
    float zC = zB * d2 + f2;

    // backward scan: Sf[s] = d[s+1]*Sf[s+1] + f[s]
    float Pb = d3 * d2 * d1;
    float Qb = (f2 * d2 + f1) * d1 + f0;
    #pragma unroll
    for (int off = 1; off < 64; off <<= 1) {
        float Pp = __shfl_down(Pb, off);
        float Qp = __shfl_down(Qb, off);
        if (lane < 64 - off) { Qb = Qp * Pb + Qb; Pb = Pp * Pb; }
    }
    float sin_ = __shfl_down(Qb, 1);
    if (lane == 63) sin_ = 0.f;
    float sC = sin_ * d3 + f2;
    float sB = sC * d2 + f1;
    float sA = sB * d1 + f0;

    float rd0 = 1.0f / Dm[db + s0];
    float rd1 = 1.0f / Dm[db + s0 + 1];
    float rd2 = 1.0f / Dm[db + s0 + 2];
    // out = (colsum + rowsum_incl - f(diag of row part excluded) - f(rowsum incl-counted diag)) / D
    out[rb + s0]     = (colsum[rb + s0]     + zA + sA - 2.f * f0) * rd0;
    out[rb + s0 + 1] = (colsum[rb + s0 + 1] + zB + sB - 2.f * f1) * rd1;
    out[rb + s0 + 2] = (colsum[rb + s0 + 2] + zC + sC - 2.f * f2) * rd2;
}

extern "C" void kernel_launch(void* const* d_in, const int* in_sizes, int n_in,
                              void* d_out, int out_size, void* d_ws, size_t ws_size,
                              hipStream_t stream) {
    const float* mask = (const float*)d_in[0];
    const float* edge = (const float*)d_in[1];
    float* out = (float*)d_out;

    float* dmat = (float*)d_ws;                 // [B,H,W]
    float* dcol = dmat + B * H * W;             // [B,H,W]
    float* Dm   = dcol + B * H * W;             // [B,H,W]
    float* csum = Dm + B * H * W;               // [B,C,H,W]

    const int ITER = 3;

    k_prep<<<(B * H * W) / (4 * 256), 256, 0, stream>>>(edge, dmat);
    k_colscan<true><<<B * (W / JT), 512, 0, stream>>>(nullptr, dmat, dcol);
    k_drow<<<(B * H) / 4, 256, 0, stream>>>(dmat, dcol, Dm);

    const int colgrid = B * C * (W / JT);       // 228
    const int rowgrid = (B * C * H) / 4;        // 3648

    k_colscan<false><<<colgrid, 512, 0, stream>>>(mask, dmat, csum);
    k_rowcomb<<<rowgrid, 256, 0, stream>>>(mask, dmat, Dm, csum, out);
    for (int it = 1; it < ITER; ++it) {
        k_colscan<false><<<colgrid, 512, 0, stream>>>(out, dmat, csum);
        k_rowcomb<<<rowgrid, 256, 0, stream>>>(out, dmat, Dm, csum, out);
    }
}